// Round 1
// baseline (2943.101 us; speedup 1.0000x reference)
//
#include <hip/hip_runtime.h>

#define NN 100000
#define EE 1600000
#define RRR 8
#define NSEG (NN*RRR)
#define F 128
#define KDIM 1152          // 8 relations * 128 + self(root) 128
#define BNEPS 1e-5f

// ----------------------------- setup kernels -----------------------------
__global__ void k_count(const int* __restrict__ dst, const int* __restrict__ et,
                        unsigned* __restrict__ cnt) {
  int e = blockIdx.x*256 + threadIdx.x;
  if (e < EE) {
    int seg = dst[e]*RRR + et[e];
    atomicAdd(&cnt[seg], 1u);
  }
}

// exclusive scan over NSEG u32: phase1 (2048/block)
__global__ void k_scan1(const unsigned* __restrict__ cnt, unsigned* __restrict__ off,
                        unsigned* __restrict__ bsum) {
  __shared__ unsigned s[256];
  int t = threadIdx.x;
  int base = blockIdx.x*2048 + t*8;
  unsigned loc[8];
  unsigned tot = 0;
#pragma unroll
  for (int j = 0; j < 8; j++) {
    unsigned v = (base+j < NSEG) ? cnt[base+j] : 0u;
    loc[j] = tot;
    tot += v;
  }
  s[t] = tot;
  __syncthreads();
  for (int d = 1; d < 256; d <<= 1) {
    unsigned v = (t >= d) ? s[t-d] : 0u;
    __syncthreads();
    s[t] += v;
    __syncthreads();
  }
  unsigned tbase = s[t] - tot;
#pragma unroll
  for (int j = 0; j < 8; j++)
    if (base+j < NSEG) off[base+j] = tbase + loc[j];
  if (t == 255) bsum[blockIdx.x] = s[255];
}

__global__ void k_scan2(unsigned* bsum, int nb) {
  __shared__ unsigned s[512];
  int t = threadIdx.x;
  unsigned v = (t < nb) ? bsum[t] : 0u;
  s[t] = v;
  __syncthreads();
  for (int d = 1; d < 512; d <<= 1) {
    unsigned u = (t >= d) ? s[t-d] : 0u;
    __syncthreads();
    s[t] += u;
    __syncthreads();
  }
  if (t < nb) bsum[t] = (t == 0) ? 0u : s[t-1];
}

__global__ void k_scan3(unsigned* off, const unsigned* __restrict__ bsum) {
  int i = blockIdx.x*256 + threadIdx.x;
  if (i < NSEG) off[i] += bsum[i >> 11];
}

__global__ void k_fill(const int* __restrict__ src, const int* __restrict__ dst,
                       const int* __restrict__ et, const unsigned* __restrict__ off,
                       unsigned* __restrict__ fillc, int* __restrict__ csr) {
  int e = blockIdx.x*256 + threadIdx.x;
  if (e < EE) {
    int seg = dst[e]*RRR + et[e];
    unsigned pos = off[seg] + atomicAdd(&fillc[seg], 1u);
    csr[pos] = src[e];
  }
}

// Wcat[k][o], k = r*128+i for r<8 (basis-combined), k = 1024+i -> root
__global__ void k_makeW(const float* __restrict__ basis, const float* __restrict__ comp,
                        const float* __restrict__ root, float* __restrict__ Wcat) {
  int r = blockIdx.x;   // 0..8
  int i = blockIdx.y;   // 0..127
  int o = threadIdx.x;  // 0..127
  float v;
  if (r < 8) {
    v = 0.f;
#pragma unroll
    for (int b = 0; b < 8; b++)
      v += comp[r*8+b] * basis[(b*F + i)*F + o];
  } else {
    v = root[i*F + o];
  }
  Wcat[(r*F + i)*F + o] = v;
}

// ----------------------------- per-layer kernels -----------------------------
// one block per node; thread t: relation r = t>>5, channels c4 = (t&31)*4
__global__ __launch_bounds__(256) void k_agg(const float* __restrict__ h,
    const unsigned* __restrict__ off, const unsigned* __restrict__ cnt,
    const int* __restrict__ csr, float* __restrict__ Mean, int base) {
  int node = base + blockIdx.x;
  int t = threadIdx.x;
  int r = t >> 5;
  int c4 = (t & 31) * 4;
  int seg = node*RRR + r;
  unsigned b0 = off[seg];
  unsigned k = cnt[seg];
  float ax = 0.f, ay = 0.f, az = 0.f, aw = 0.f;
  for (unsigned j = 0; j < k; j++) {
    const float4 v = *(const float4*)&h[(size_t)csr[b0+j]*F + c4];
    ax += v.x; ay += v.y; az += v.z; aw += v.w;
  }
  float inv = (k > 0u) ? 1.f/(float)k : 0.f;
  size_t mrow = (size_t)(node - base) * KDIM;
  *(float4*)&Mean[mrow + r*F + c4] = make_float4(ax*inv, ay*inv, az*inv, aw*inv);
  if (r == 0) {
    *(float4*)&Mean[mrow + 1024 + c4] = *(const float4*)&h[(size_t)node*F + c4];
  }
}

// C[cc x 128] = Mean[cc x 1152] @ Wcat[1152 x 128] + bias
// block 256 thr, BM=128, BK=32, micro 8x8 (cols split o0 / o0+64)
__global__ __launch_bounds__(256) void k_gemm(const float* __restrict__ Mean,
    const float* __restrict__ Wcat, const float* __restrict__ bias,
    float* __restrict__ outp, int outBase, int count) {
  __shared__ float As[128][36];
  __shared__ float Ws[32][132];
  int t = threadIdx.x;
  int tileRow = blockIdx.x * 128;
  int m0 = (t >> 4) * 8;
  int o0 = (t & 15) * 4;
  float acc[8][8];
#pragma unroll
  for (int i = 0; i < 8; i++)
#pragma unroll
    for (int j = 0; j < 8; j++) acc[i][j] = 0.f;

  int ar = t >> 3;          // 0..31
  int ak = (t & 7) * 4;     // 0..28
  int wk = t >> 3;          // 0..31
  int wo = (t & 7) * 16;    // 0..112

  for (int kt = 0; kt < KDIM; kt += 32) {
#pragma unroll
    for (int rr = 0; rr < 4; rr++) {
      int row = ar + rr*32;
      int gr = tileRow + row;
      int grc = (gr < count) ? gr : 0;
      const float4 v = *(const float4*)&Mean[(size_t)grc*KDIM + kt + ak];
      *(float4*)&As[row][ak] = v;
    }
#pragma unroll
    for (int c = 0; c < 4; c++) {
      const float4 v = *(const float4*)&Wcat[(size_t)(kt + wk)*F + wo + c*4];
      *(float4*)&Ws[wk][wo + c*4] = v;
    }
    __syncthreads();
#pragma unroll
    for (int kk = 0; kk < 32; kk += 4) {
      float4 a[8];
#pragma unroll
      for (int i = 0; i < 8; i++) a[i] = *(const float4*)&As[m0+i][kk];
#pragma unroll
      for (int kx = 0; kx < 4; kx++) {
        float4 b0v = *(const float4*)&Ws[kk+kx][o0];
        float4 b1v = *(const float4*)&Ws[kk+kx][64+o0];
#pragma unroll
        for (int i = 0; i < 8; i++) {
          float av = (kx==0) ? a[i].x : (kx==1) ? a[i].y : (kx==2) ? a[i].z : a[i].w;
          acc[i][0] += av*b0v.x; acc[i][1] += av*b0v.y;
          acc[i][2] += av*b0v.z; acc[i][3] += av*b0v.w;
          acc[i][4] += av*b1v.x; acc[i][5] += av*b1v.y;
          acc[i][6] += av*b1v.z; acc[i][7] += av*b1v.w;
        }
      }
    }
    __syncthreads();
  }
  float4 ba = *(const float4*)&bias[o0];
  float4 bb = *(const float4*)&bias[64+o0];
#pragma unroll
  for (int i = 0; i < 8; i++) {
    int gr = tileRow + m0 + i;
    if (gr < count) {
      float4 v0 = make_float4(acc[i][0]+ba.x, acc[i][1]+ba.y, acc[i][2]+ba.z, acc[i][3]+ba.w);
      float4 v1 = make_float4(acc[i][4]+bb.x, acc[i][5]+bb.y, acc[i][6]+bb.z, acc[i][7]+bb.w);
      *(float4*)&outp[(size_t)(outBase+gr)*F + o0] = v0;
      *(float4*)&outp[(size_t)(outBase+gr)*F + 64 + o0] = v1;
    }
  }
}

__global__ __launch_bounds__(256) void k_bnstats(const float* __restrict__ h,
                                                 float* __restrict__ stats) {
  __shared__ float ls[256], lq[256];
  int t = threadIdx.x;
  int c = t & 127;
  int rh = t >> 7;
  int start = blockIdx.x * 512;
  int end = start + 512; if (end > NN) end = NN;
  float s = 0.f, q = 0.f;
  for (int row = start + rh; row < end; row += 2) {
    float v = h[(size_t)row*F + c];
    s += v; q += v*v;
  }
  ls[t] = s; lq[t] = q;
  __syncthreads();
  if (t < 128) {
    s = ls[t] + ls[t+128];
    q = lq[t] + lq[t+128];
    atomicAdd(&stats[c], s);
    atomicAdd(&stats[128+c], q);
  }
}

__global__ __launch_bounds__(256) void k_bnapply(const float* __restrict__ h,
    const float* __restrict__ stats, const float* __restrict__ gamma,
    const float* __restrict__ beta, float* __restrict__ outp) {
  int idx = blockIdx.x*256 + threadIdx.x;
  if (idx >= NN*32) return;
  int row = idx >> 5;
  int c4 = (idx & 31) * 4;
  float4 v  = *(const float4*)&h[(size_t)row*F + c4];
  float4 sm = *(const float4*)&stats[c4];
  float4 sq = *(const float4*)&stats[128 + c4];
  float4 g  = *(const float4*)&gamma[c4];
  float4 bt = *(const float4*)&beta[c4];
  const float invN = 1.f / (float)NN;
  float r0;
  float4 y;
  { float m = sm.x*invN; float var = sq.x*invN - m*m; r0 = rsqrtf(var + BNEPS);
    float z = (v.x - m)*r0*g.x + bt.x; y.x = (z > 0.f) ? z : 0.1f*z; }
  { float m = sm.y*invN; float var = sq.y*invN - m*m; r0 = rsqrtf(var + BNEPS);
    float z = (v.y - m)*r0*g.y + bt.y; y.y = (z > 0.f) ? z : 0.1f*z; }
  { float m = sm.z*invN; float var = sq.z*invN - m*m; r0 = rsqrtf(var + BNEPS);
    float z = (v.z - m)*r0*g.z + bt.z; y.z = (z > 0.f) ? z : 0.1f*z; }
  { float m = sm.w*invN; float var = sq.w*invN - m*m; r0 = rsqrtf(var + BNEPS);
    float z = (v.w - m)*r0*g.w + bt.w; y.w = (z > 0.f) ? z : 0.1f*z; }
  *(float4*)&outp[(size_t)row*F + c4] = y;
}

__global__ __launch_bounds__(256) void k_l2norm(float* __restrict__ outp) {
  __shared__ float s[256];
  int t = threadIdx.x;
  int g = t >> 7;
  int c = t & 127;
  int row = blockIdx.x*2 + g;
  float v = outp[(size_t)row*F + c];
  s[t] = v*v;
  __syncthreads();
  for (int o = 64; o > 0; o >>= 1) {
    if ((t & 127) < o) s[t] += s[t+o];
    __syncthreads();
  }
  float nrm = fmaxf(sqrtf(s[t & ~127]), 1e-12f);
  outp[(size_t)row*F + c] = v / nrm;
}

// ----------------------------- host launcher -----------------------------
extern "C" void kernel_launch(void* const* d_in, const int* in_sizes, int n_in,
                              void* d_out, int out_size, void* d_ws, size_t ws_size,
                              hipStream_t stream) {
  const float* x      = (const float*)d_in[0];
  const int*   ei     = (const int*)d_in[1];
  const int*   etp    = (const int*)d_in[2];
  const float* basis[3] = {(const float*)d_in[3], (const float*)d_in[7],  (const float*)d_in[11]};
  const float* comp[3]  = {(const float*)d_in[4], (const float*)d_in[8],  (const float*)d_in[12]};
  const float* root[3]  = {(const float*)d_in[5], (const float*)d_in[9],  (const float*)d_in[13]};
  const float* bias[3]  = {(const float*)d_in[6], (const float*)d_in[10], (const float*)d_in[14]};
  const float* gamma[2] = {(const float*)d_in[15], (const float*)d_in[17]};
  const float* beta[2]  = {(const float*)d_in[16], (const float*)d_in[18]};
  const int* srcv = ei;
  const int* dstv = ei + EE;
  float* out = (float*)d_out;

  char* w = (char*)d_ws;
  size_t p = 0;
  auto take = [&](size_t bytes) -> void* {
    void* q = w + p;
    p = (p + bytes + 255) & ~(size_t)255;
    return q;
  };
  unsigned* cnt   = (unsigned*)take((size_t)NSEG*4);
  unsigned* off   = (unsigned*)take((size_t)NSEG*4);
  unsigned* fillc = (unsigned*)take((size_t)NSEG*4);
  int*      csr   = (int*)     take((size_t)EE*4);
  unsigned* bsum  = (unsigned*)take(1024*4);
  float*    Wcat  = (float*)   take((size_t)KDIM*F*4);
  float*    stats = (float*)   take(256*4);
  float*    wsA   = (float*)   take((size_t)NN*F*4);
  float*    wsB   = (float*)   take((size_t)NN*F*4);
  size_t avail = (ws_size > p) ? (ws_size - p) : 0;
  long long chmax = (long long)(avail / ((size_t)KDIM*4));
  int CH = (chmax > NN) ? NN : (int)chmax;
  if (CH < 1) CH = 1;
  float* Mean = (float*)(w + p);

  // -------- static graph preprocessing --------
  hipMemsetAsync(cnt,   0, (size_t)NSEG*4, stream);
  hipMemsetAsync(fillc, 0, (size_t)NSEG*4, stream);
  k_count<<<(EE+255)/256, 256, 0, stream>>>(dstv, etp, cnt);
  int nb1 = (NSEG + 2047)/2048;
  k_scan1<<<nb1, 256, 0, stream>>>(cnt, off, bsum);
  k_scan2<<<1, 512, 0, stream>>>(bsum, nb1);
  k_scan3<<<(NSEG+255)/256, 256, 0, stream>>>(off, bsum);
  k_fill<<<(EE+255)/256, 256, 0, stream>>>(srcv, dstv, etp, off, fillc, csr);

  // -------- 3 layers --------
  for (int l = 0; l < 3; l++) {
    const float* hin = (l == 0) ? x : wsB;
    float* hraw = (l == 2) ? out : wsA;
    dim3 gw(9, 128);
    k_makeW<<<gw, 128, 0, stream>>>(basis[l], comp[l], root[l], Wcat);
    for (int b0n = 0; b0n < NN; b0n += CH) {
      int cc = NN - b0n; if (cc > CH) cc = CH;
      k_agg<<<cc, 256, 0, stream>>>(hin, off, cnt, csr, Mean, b0n);
      k_gemm<<<(cc+127)/128, 256, 0, stream>>>(Mean, Wcat, bias[l], hraw, b0n, cc);
    }
    if (l < 2) {
      hipMemsetAsync(stats, 0, 256*4, stream);
      k_bnstats<<<(NN+511)/512, 256, 0, stream>>>(hraw, stats);
      k_bnapply<<<(NN*32+255)/256, 256, 0, stream>>>(hraw, stats, gamma[l], beta[l], wsB);
    }
  }
  k_l2norm<<<NN/2, 256, 0, stream>>>(out);
}

// Round 2
// 1303.915 us; speedup vs baseline: 2.2571x; 2.2571x over previous
//
#include <hip/hip_runtime.h>

#define NN 100000
#define EE 1600000
#define RRR 8
#define NSEG (NN*RRR)
#define F 128
#define KDIM 1152          // 8 relations * 128 + self(root) 128
#define NKT 36             // KDIM/32
#define BNEPS 1e-5f

typedef __attribute__((ext_vector_type(8))) short bf16x8;
typedef __attribute__((ext_vector_type(4))) float f32x4;

static __device__ __forceinline__ unsigned short bf16r(float f) {
  unsigned u = __float_as_uint(f);
  u += 0x7fffu + ((u >> 16) & 1u);
  return (unsigned short)(u >> 16);
}

// ----------------------------- setup kernels -----------------------------
__global__ void k_count(const int* __restrict__ dst, const int* __restrict__ et,
                        unsigned* __restrict__ cnt) {
  int e = blockIdx.x*256 + threadIdx.x;
  if (e < EE) {
    int seg = dst[e]*RRR + et[e];
    atomicAdd(&cnt[seg], 1u);
  }
}

__global__ void k_scan1(const unsigned* __restrict__ cnt, unsigned* __restrict__ off,
                        unsigned* __restrict__ bsum) {
  __shared__ unsigned s[256];
  int t = threadIdx.x;
  int base = blockIdx.x*2048 + t*8;
  unsigned loc[8];
  unsigned tot = 0;
#pragma unroll
  for (int j = 0; j < 8; j++) {
    unsigned v = (base+j < NSEG) ? cnt[base+j] : 0u;
    loc[j] = tot;
    tot += v;
  }
  s[t] = tot;
  __syncthreads();
  for (int d = 1; d < 256; d <<= 1) {
    unsigned v = (t >= d) ? s[t-d] : 0u;
    __syncthreads();
    s[t] += v;
    __syncthreads();
  }
  unsigned tbase = s[t] - tot;
#pragma unroll
  for (int j = 0; j < 8; j++)
    if (base+j < NSEG) off[base+j] = tbase + loc[j];
  if (t == 255) bsum[blockIdx.x] = s[255];
}

__global__ void k_scan2(unsigned* bsum, int nb) {
  __shared__ unsigned s[512];
  int t = threadIdx.x;
  unsigned v = (t < nb) ? bsum[t] : 0u;
  s[t] = v;
  __syncthreads();
  for (int d = 1; d < 512; d <<= 1) {
    unsigned u = (t >= d) ? s[t-d] : 0u;
    __syncthreads();
    s[t] += u;
    __syncthreads();
  }
  if (t < nb) bsum[t] = (t == 0) ? 0u : s[t-1];
}

__global__ void k_scan3(unsigned* off, const unsigned* __restrict__ bsum) {
  int i = blockIdx.x*256 + threadIdx.x;
  if (i < NSEG) off[i] += bsum[i >> 11];
}

__global__ void k_fill(const int* __restrict__ src, const int* __restrict__ dst,
                       const int* __restrict__ et, const unsigned* __restrict__ off,
                       unsigned* __restrict__ fillc, int* __restrict__ csr) {
  int e = blockIdx.x*256 + threadIdx.x;
  if (e < EE) {
    int seg = dst[e]*RRR + et[e];
    unsigned pos = off[seg] + atomicAdd(&fillc[seg], 1u);
    csr[pos] = src[e];
  }
}

// WB in B-fragment layout (bf16): WB[((kt*8 + ct)*64 + lane)*8 + j]
//   = Wcat[k][o],  k = kt*32 + (lane>>4)*8 + j,  o = ct*16 + (lane&15)
// Wcat semantics: k<1024 -> W[r=k>>7][i=k&127][o] = sum_b comp[r][b]*basis[b][i][o]
//                 k>=1024 -> root[k-1024][o]
__global__ void k_makeW(const float* __restrict__ basis, const float* __restrict__ comp,
                        const float* __restrict__ root, unsigned short* __restrict__ WB) {
  int kt = blockIdx.x;        // 0..35
  int ct = blockIdx.y;        // 0..7
  int lane = threadIdx.x;     // 0..63
  int o = ct*16 + (lane & 15);
  int kbase = kt*32 + (lane >> 4)*8;
  unsigned short v[8];
#pragma unroll
  for (int j = 0; j < 8; j++) {
    int k = kbase + j;
    float val;
    if (k < 1024) {
      int r = k >> 7, i = k & 127;
      val = 0.f;
#pragma unroll
      for (int b = 0; b < 8; b++)
        val += comp[r*8+b] * basis[(b*F + i)*F + o];
    } else {
      val = root[(k - 1024)*F + o];
    }
    v[j] = bf16r(val);
  }
  unsigned short* dst = WB + ((size_t)(kt*8 + ct)*64 + lane)*8;
#pragma unroll
  for (int j = 0; j < 8; j++) dst[j] = v[j];
}

// ----------------------------- per-layer kernels -----------------------------
// one block per node; thread t: relation r = t>>5, channels c4 = (t&31)*4
// Mean rows stored in bf16.
__global__ __launch_bounds__(256) void k_agg(const float* __restrict__ h,
    const unsigned* __restrict__ off, const unsigned* __restrict__ cnt,
    const int* __restrict__ csr, unsigned short* __restrict__ Mean, int base) {
  int node = base + blockIdx.x;
  int t = threadIdx.x;
  int r = t >> 5;
  int c4 = (t & 31) * 4;
  int seg = node*RRR + r;
  unsigned b0 = off[seg];
  unsigned k = cnt[seg];
  float ax = 0.f, ay = 0.f, az = 0.f, aw = 0.f;
  for (unsigned j = 0; j < k; j++) {
    const float4 v = *(const float4*)&h[(size_t)csr[b0+j]*F + c4];
    ax += v.x; ay += v.y; az += v.z; aw += v.w;
  }
  float inv = (k > 0u) ? 1.f/(float)k : 0.f;
  size_t mrow = (size_t)(node - base) * KDIM;
  ushort4 ov;
  ov.x = bf16r(ax*inv); ov.y = bf16r(ay*inv);
  ov.z = bf16r(az*inv); ov.w = bf16r(aw*inv);
  *(ushort4*)&Mean[mrow + r*F + c4] = ov;
  if (r == 0) {
    const float4 s = *(const float4*)&h[(size_t)node*F + c4];
    ushort4 sv;
    sv.x = bf16r(s.x); sv.y = bf16r(s.y); sv.z = bf16r(s.z); sv.w = bf16r(s.w);
    *(ushort4*)&Mean[mrow + 1024 + c4] = sv;
  }
}

// C[count x 128] = Mean[count x 1152](bf16) @ W(bf16, fragment layout) + bias
// 256 thr = 4 waves; wave w owns rows [blk*128 + w*32, +32), all 128 cols.
// No LDS, no barriers. A frags direct from Mean; B frags from pre-swizzled WB.
__global__ __launch_bounds__(256) void k_gemm(const unsigned short* __restrict__ Mean,
    const unsigned short* __restrict__ WB, const float* __restrict__ bias,
    float* __restrict__ outp, int outBase, int count) {
  int t = threadIdx.x;
  int wave = t >> 6;
  int lane = t & 63;
  int rbase = blockIdx.x*128 + wave*32;
  int rlo = lane & 15;
  int kg = lane >> 4;
  int r0 = rbase + rlo;       if (r0 > count-1) r0 = count-1;
  int r1 = rbase + 16 + rlo;  if (r1 > count-1) r1 = count-1;
  const unsigned short* a0p = Mean + (size_t)r0*KDIM + kg*8;
  const unsigned short* a1p = Mean + (size_t)r1*KDIM + kg*8;
  const unsigned short* bp  = WB + (size_t)lane*8;

  f32x4 acc[2][8];
#pragma unroll
  for (int i = 0; i < 2; i++)
#pragma unroll
    for (int j = 0; j < 8; j++) acc[i][j] = (f32x4){0.f,0.f,0.f,0.f};

  for (int kt = 0; kt < NKT; kt++) {
    bf16x8 a0 = *(const bf16x8*)(a0p + kt*32);
    bf16x8 a1 = *(const bf16x8*)(a1p + kt*32);
#pragma unroll
    for (int ct = 0; ct < 8; ct++) {
      bf16x8 b = *(const bf16x8*)(bp + (size_t)(kt*8 + ct)*64*8);
      acc[0][ct] = __builtin_amdgcn_mfma_f32_16x16x32_bf16(a0, b, acc[0][ct], 0, 0, 0);
      acc[1][ct] = __builtin_amdgcn_mfma_f32_16x16x32_bf16(a1, b, acc[1][ct], 0, 0, 0);
    }
  }

  float bv[8];
#pragma unroll
  for (int ct = 0; ct < 8; ct++) bv[ct] = bias[ct*16 + rlo];

  // C/D layout: col = lane&15, row = (lane>>4)*4 + reg
#pragma unroll
  for (int rt = 0; rt < 2; rt++) {
#pragma unroll
    for (int i = 0; i < 4; i++) {
      int row = rbase + rt*16 + kg*4 + i;
      if (row < count) {
        float* orow = outp + (size_t)(outBase + row)*F;
#pragma unroll
        for (int ct = 0; ct < 8; ct++)
          orow[ct*16 + rlo] = acc[rt][ct][i] + bv[ct];
      }
    }
  }
}

__global__ __launch_bounds__(256) void k_bnstats(const float* __restrict__ h,
                                                 float* __restrict__ stats) {
  __shared__ float ls[256], lq[256];
  int t = threadIdx.x;
  int c = t & 127;
  int rh = t >> 7;
  int start = blockIdx.x * 512;
  int end = start + 512; if (end > NN) end = NN;
  float s = 0.f, q = 0.f;
  for (int row = start + rh; row < end; row += 2) {
    float v = h[(size_t)row*F + c];
    s += v; q += v*v;
  }
  ls[t] = s; lq[t] = q;
  __syncthreads();
  if (t < 128) {
    s = ls[t] + ls[t+128];
    q = lq[t] + lq[t+128];
    atomicAdd(&stats[c], s);
    atomicAdd(&stats[128+c], q);
  }
}

__global__ __launch_bounds__(256) void k_bnapply(const float* __restrict__ h,
    const float* __restrict__ stats, const float* __restrict__ gamma,
    const float* __restrict__ beta, float* __restrict__ outp) {
  int idx = blockIdx.x*256 + threadIdx.x;
  if (idx >= NN*32) return;
  int row = idx >> 5;
  int c4 = (idx & 31) * 4;
  float4 v  = *(const float4*)&h[(size_t)row*F + c4];
  float4 sm = *(const float4*)&stats[c4];
  float4 sq = *(const float4*)&stats[128 + c4];
  float4 g  = *(const float4*)&gamma[c4];
  float4 bt = *(const float4*)&beta[c4];
  const float invN = 1.f / (float)NN;
  float r0;
  float4 y;
  { float m = sm.x*invN; float var = sq.x*invN - m*m; r0 = rsqrtf(var + BNEPS);
    float z = (v.x - m)*r0*g.x + bt.x; y.x = (z > 0.f) ? z : 0.1f*z; }
  { float m = sm.y*invN; float var = sq.y*invN - m*m; r0 = rsqrtf(var + BNEPS);
    float z = (v.y - m)*r0*g.y + bt.y; y.y = (z > 0.f) ? z : 0.1f*z; }
  { float m = sm.z*invN; float var = sq.z*invN - m*m; r0 = rsqrtf(var + BNEPS);
    float z = (v.z - m)*r0*g.z + bt.z; y.z = (z > 0.f) ? z : 0.1f*z; }
  { float m = sm.w*invN; float var = sq.w*invN - m*m; r0 = rsqrtf(var + BNEPS);
    float z = (v.w - m)*r0*g.w + bt.w; y.w = (z > 0.f) ? z : 0.1f*z; }
  *(float4*)&outp[(size_t)row*F + c4] = y;
}

__global__ __launch_bounds__(256) void k_l2norm(float* __restrict__ outp) {
  __shared__ float s[256];
  int t = threadIdx.x;
  int g = t >> 7;
  int c = t & 127;
  int row = blockIdx.x*2 + g;
  float v = outp[(size_t)row*F + c];
  s[t] = v*v;
  __syncthreads();
  for (int o = 64; o > 0; o >>= 1) {
    if ((t & 127) < o) s[t] += s[t+o];
    __syncthreads();
  }
  float nrm = fmaxf(sqrtf(s[t & ~127]), 1e-12f);
  outp[(size_t)row*F + c] = v / nrm;
}

// ----------------------------- host launcher -----------------------------
extern "C" void kernel_launch(void* const* d_in, const int* in_sizes, int n_in,
                              void* d_out, int out_size, void* d_ws, size_t ws_size,
                              hipStream_t stream) {
  const float* x      = (const float*)d_in[0];
  const int*   ei     = (const int*)d_in[1];
  const int*   etp    = (const int*)d_in[2];
  const float* basis[3] = {(const float*)d_in[3], (const float*)d_in[7],  (const float*)d_in[11]};
  const float* comp[3]  = {(const float*)d_in[4], (const float*)d_in[8],  (const float*)d_in[12]};
  const float* root[3]  = {(const float*)d_in[5], (const float*)d_in[9],  (const float*)d_in[13]};
  const float* bias[3]  = {(const float*)d_in[6], (const float*)d_in[10], (const float*)d_in[14]};
  const float* gamma[2] = {(const float*)d_in[15], (const float*)d_in[17]};
  const float* beta[2]  = {(const float*)d_in[16], (const float*)d_in[18]};
  const int* srcv = ei;
  const int* dstv = ei + EE;
  float* out = (float*)d_out;

  char* w = (char*)d_ws;
  size_t p = 0;
  auto take = [&](size_t bytes) -> void* {
    void* q = w + p;
    p = (p + bytes + 255) & ~(size_t)255;
    return q;
  };
  unsigned* cnt   = (unsigned*)take((size_t)NSEG*4);
  unsigned* off   = (unsigned*)take((size_t)NSEG*4);
  unsigned* fillc = (unsigned*)take((size_t)NSEG*4);
  int*      csr   = (int*)     take((size_t)EE*4);
  unsigned* bsum  = (unsigned*)take(1024*4);
  unsigned short* WB = (unsigned short*)take((size_t)KDIM*F*2);
  float*    stats = (float*)   take(256*4);
  float*    wsA   = (float*)   take((size_t)NN*F*4);
  float*    wsB   = (float*)   take((size_t)NN*F*4);
  size_t avail = (ws_size > p) ? (ws_size - p) : 0;
  long long chmax = (long long)(avail / ((size_t)KDIM*2));
  int CH = (chmax > NN) ? NN : (int)chmax;
  if (CH < 1) CH = 1;
  unsigned short* Mean = (unsigned short*)(w + p);

  // -------- static graph preprocessing --------
  hipMemsetAsync(cnt,   0, (size_t)NSEG*4, stream);
  hipMemsetAsync(fillc, 0, (size_t)NSEG*4, stream);
  k_count<<<(EE+255)/256, 256, 0, stream>>>(dstv, etp, cnt);
  int nb1 = (NSEG + 2047)/2048;
  k_scan1<<<nb1, 256, 0, stream>>>(cnt, off, bsum);
  k_scan2<<<1, 512, 0, stream>>>(bsum, nb1);
  k_scan3<<<(NSEG+255)/256, 256, 0, stream>>>(off, bsum);
  k_fill<<<(EE+255)/256, 256, 0, stream>>>(srcv, dstv, etp, off, fillc, csr);

  // -------- 3 layers --------
  for (int l = 0; l < 3; l++) {
    const float* hin = (l == 0) ? x : wsB;
    float* hraw = (l == 2) ? out : wsA;
    dim3 gw(NKT, 8);
    k_makeW<<<gw, 64, 0, stream>>>(basis[l], comp[l], root[l], WB);
    for (int b0n = 0; b0n < NN; b0n += CH) {
      int cc = NN - b0n; if (cc > CH) cc = CH;
      k_agg<<<cc, 256, 0, stream>>>(hin, off, cnt, csr, Mean, b0n);
      k_gemm<<<(cc+127)/128, 256, 0, stream>>>(Mean, WB, bias[l], hraw, b0n, cc);
    }
    if (l < 2) {
      hipMemsetAsync(stats, 0, 256*4, stream);
      k_bnstats<<<(NN+511)/512, 256, 0, stream>>>(hraw, stats);
      k_bnapply<<<(NN*32+255)/256, 256, 0, stream>>>(hraw, stats, gamma[l], beta[l], wsB);
    }
  }
  k_l2norm<<<NN/2, 256, 0, stream>>>(out);
}

// Round 3
// 1161.834 us; speedup vs baseline: 2.5332x; 1.1223x over previous
//
#include <hip/hip_runtime.h>

#define NN 100000
#define EE 1600000
#define RRR 8
#define NSEG (NN*RRR)
#define F 128
#define KDIM 1152          // 8 relations * 128 + self(root) 128
#define NKT 36             // KDIM/32
#define NT 64              // nodes per fused block
#define BNEPS 1e-5f

typedef __attribute__((ext_vector_type(8))) short bf16x8;
typedef __attribute__((ext_vector_type(4))) float f32x4;

static __device__ __forceinline__ unsigned short bf16r(float f) {
  unsigned u = __float_as_uint(f);
  u += 0x7fffu + ((u >> 16) & 1u);
  return (unsigned short)(u >> 16);
}

// XOR-swizzle on linear LDS byte address: row = addr>>8 (256 B/row),
// flip 16B-slot bits by (row&7) to kill the 32-way column conflict (G4/m214).
static __device__ __forceinline__ int swz(int a) {
  return a ^ (((a >> 8) & 7) << 4);
}

// ----------------------------- setup kernels -----------------------------
__global__ void k_count(const int* __restrict__ dst, const int* __restrict__ et,
                        unsigned* __restrict__ cnt) {
  int e = blockIdx.x*256 + threadIdx.x;
  if (e < EE) {
    int seg = dst[e]*RRR + et[e];
    atomicAdd(&cnt[seg], 1u);
  }
}

__global__ void k_scan1(const unsigned* __restrict__ cnt, unsigned* __restrict__ off,
                        unsigned* __restrict__ bsum) {
  __shared__ unsigned s[256];
  int t = threadIdx.x;
  int base = blockIdx.x*2048 + t*8;
  unsigned loc[8];
  unsigned tot = 0;
#pragma unroll
  for (int j = 0; j < 8; j++) {
    unsigned v = (base+j < NSEG) ? cnt[base+j] : 0u;
    loc[j] = tot;
    tot += v;
  }
  s[t] = tot;
  __syncthreads();
  for (int d = 1; d < 256; d <<= 1) {
    unsigned v = (t >= d) ? s[t-d] : 0u;
    __syncthreads();
    s[t] += v;
    __syncthreads();
  }
  unsigned tbase = s[t] - tot;
#pragma unroll
  for (int j = 0; j < 8; j++)
    if (base+j < NSEG) off[base+j] = tbase + loc[j];
  if (t == 255) bsum[blockIdx.x] = s[255];
}

__global__ void k_scan2(unsigned* bsum, int nb) {
  __shared__ unsigned s[512];
  int t = threadIdx.x;
  unsigned v = (t < nb) ? bsum[t] : 0u;
  s[t] = v;
  __syncthreads();
  for (int d = 1; d < 512; d <<= 1) {
    unsigned u = (t >= d) ? s[t-d] : 0u;
    __syncthreads();
    s[t] += u;
    __syncthreads();
  }
  if (t < nb) bsum[t] = (t == 0) ? 0u : s[t-1];
}

__global__ void k_scan3(unsigned* off, const unsigned* __restrict__ bsum) {
  int i = blockIdx.x*256 + threadIdx.x;
  if (i < NSEG) off[i] += bsum[i >> 11];
}

__global__ void k_fill(const int* __restrict__ src, const int* __restrict__ dst,
                       const int* __restrict__ et, const unsigned* __restrict__ off,
                       unsigned* __restrict__ fillc, int* __restrict__ csr) {
  int e = blockIdx.x*256 + threadIdx.x;
  if (e < EE) {
    int seg = dst[e]*RRR + et[e];
    unsigned pos = off[seg] + atomicAdd(&fillc[seg], 1u);
    csr[pos] = src[e];
  }
}

// WB in B-fragment layout (bf16): WB[((kt*8 + ct)*64 + lane)*8 + j]
//   = Wcat[k][o],  k = kt*32 + (lane>>4)*8 + j,  o = ct*16 + (lane&15)
__global__ void k_makeW(const float* __restrict__ basis, const float* __restrict__ comp,
                        const float* __restrict__ root, unsigned short* __restrict__ WB) {
  int kt = blockIdx.x;        // 0..35
  int ct = blockIdx.y;        // 0..7
  int lane = threadIdx.x;     // 0..63
  int o = ct*16 + (lane & 15);
  int kbase = kt*32 + (lane >> 4)*8;
  unsigned short v[8];
#pragma unroll
  for (int j = 0; j < 8; j++) {
    int k = kbase + j;
    float val;
    if (k < 1024) {
      int r = k >> 7, i = k & 127;
      val = 0.f;
#pragma unroll
      for (int b = 0; b < 8; b++)
        val += comp[r*8+b] * basis[(b*F + i)*F + o];
    } else {
      val = root[(k - 1024)*F + o];
    }
    v[j] = bf16r(val);
  }
  unsigned short* dst = WB + ((size_t)(kt*8 + ct)*64 + lane)*8;
#pragma unroll
  for (int j = 0; j < 8; j++) dst[j] = v[j];
}

// ----------------------------- fused agg + GEMM -----------------------------
// Block: 64 nodes, 256 threads (4 waves). For each of 9 K-chunks (8 relations
// + self/root): gather means into LDS [64][128] bf16 (swizzled), then MFMA
// against WB chunk. No Mean in HBM.
// Phase A thread map: nl = t>>2 (node 0..63), q = t&3 (channel quarter).
// Phase B wave map: wave w = rows w*16..w*16+15, all 128 cols.
__global__ __launch_bounds__(256) void k_fused(const float* __restrict__ h,
    const unsigned* __restrict__ off, const unsigned* __restrict__ cnt,
    const int* __restrict__ csr, const unsigned short* __restrict__ WB,
    const float* __restrict__ bias, float* __restrict__ outp, int count) {
  __shared__ char lds[NT * 256];
  int t = threadIdx.x;
  int nl = t >> 2, q = t & 3;
  int wave = t >> 6, lane = t & 63;
  int rlo = lane & 15, kg = lane >> 4;
  int n0 = blockIdx.x * NT;
  int node = n0 + nl;
  int nodec = (node < count) ? node : (count - 1);

  f32x4 acc[8];
#pragma unroll
  for (int j = 0; j < 8; j++) acc[j] = (f32x4){0.f, 0.f, 0.f, 0.f};

  for (int c = 0; c < 9; c++) {
    float sx[8], sy[8], sz[8], sw[8];
#pragma unroll
    for (int u = 0; u < 8; u++) { sx[u] = 0.f; sy[u] = 0.f; sz[u] = 0.f; sw[u] = 0.f; }
    if (c < 8) {
      int seg = nodec * RRR + c;
      unsigned b0 = off[seg];
      unsigned kk = cnt[seg];
      unsigned j = 0;
      for (; j + 2 <= kk; j += 2) {
        int iA = csr[b0 + j];
        int iB = csr[b0 + j + 1];
        const float* ra = h + (size_t)iA * F + q * 4;
        const float* rb = h + (size_t)iB * F + q * 4;
#pragma unroll
        for (int u = 0; u < 8; u++) {
          float4 va = *(const float4*)(ra + u * 16);
          float4 vb = *(const float4*)(rb + u * 16);
          sx[u] += va.x + vb.x; sy[u] += va.y + vb.y;
          sz[u] += va.z + vb.z; sw[u] += va.w + vb.w;
        }
      }
      if (j < kk) {
        int iA = csr[b0 + j];
        const float* ra = h + (size_t)iA * F + q * 4;
#pragma unroll
        for (int u = 0; u < 8; u++) {
          float4 va = *(const float4*)(ra + u * 16);
          sx[u] += va.x; sy[u] += va.y; sz[u] += va.z; sw[u] += va.w;
        }
      }
      float inv = kk ? (1.f / (float)kk) : 0.f;
#pragma unroll
      for (int u = 0; u < 8; u++) { sx[u] *= inv; sy[u] *= inv; sz[u] *= inv; sw[u] *= inv; }
    } else {
      const float* ra = h + (size_t)nodec * F + q * 4;
#pragma unroll
      for (int u = 0; u < 8; u++) {
        float4 va = *(const float4*)(ra + u * 16);
        sx[u] = va.x; sy[u] = va.y; sz[u] = va.z; sw[u] = va.w;
      }
    }
    __syncthreads();   // previous chunk's MFMA reads done
#pragma unroll
    for (int u = 0; u < 8; u++) {
      ushort4 w4;
      w4.x = bf16r(sx[u]); w4.y = bf16r(sy[u]);
      w4.z = bf16r(sz[u]); w4.w = bf16r(sw[u]);
      // linear byte: row nl, channel slot (u*4+q) -> 8 bytes
      *(ushort4*)(lds + swz(nl * 256 + (u * 4 + q) * 8)) = w4;
    }
    __syncthreads();
#pragma unroll
    for (int kt = 0; kt < 4; kt++) {
      bf16x8 a = *(const bf16x8*)(lds + swz((wave * 16 + rlo) * 256 + kt * 64 + kg * 16));
      int KT = c * 4 + kt;
      const unsigned short* bp = WB + ((size_t)(KT * 8) * 64 + lane) * 8;
#pragma unroll
      for (int ct = 0; ct < 8; ct++) {
        bf16x8 b = *(const bf16x8*)(bp + (size_t)ct * 64 * 8);
        acc[ct] = __builtin_amdgcn_mfma_f32_16x16x32_bf16(a, b, acc[ct], 0, 0, 0);
      }
    }
  }

  float bv[8];
#pragma unroll
  for (int ct = 0; ct < 8; ct++) bv[ct] = bias[ct * 16 + rlo];
  // C/D layout: col = lane&15, row = (lane>>4)*4 + i
#pragma unroll
  for (int i = 0; i < 4; i++) {
    int row = n0 + wave * 16 + kg * 4 + i;
    if (row < count) {
      float* orow = outp + (size_t)row * F;
#pragma unroll
      for (int ct = 0; ct < 8; ct++)
        orow[ct * 16 + rlo] = acc[ct][i] + bv[ct];
    }
  }
}

// ----------------------------- BN / norm -----------------------------
__global__ __launch_bounds__(256) void k_bnstats(const float* __restrict__ h,
                                                 float* __restrict__ stats) {
  __shared__ float ls[256], lq[256];
  int t = threadIdx.x;
  int c = t & 127;
  int rh = t >> 7;
  int start = blockIdx.x * 512;
  int end = start + 512; if (end > NN) end = NN;
  float s = 0.f, q = 0.f;
  for (int row = start + rh; row < end; row += 2) {
    float v = h[(size_t)row*F + c];
    s += v; q += v*v;
  }
  ls[t] = s; lq[t] = q;
  __syncthreads();
  if (t < 128) {
    s = ls[t] + ls[t+128];
    q = lq[t] + lq[t+128];
    atomicAdd(&stats[c], s);
    atomicAdd(&stats[128+c], q);
  }
}

__global__ __launch_bounds__(256) void k_bnapply(const float* __restrict__ h,
    const float* __restrict__ stats, const float* __restrict__ gamma,
    const float* __restrict__ beta, float* __restrict__ outp) {
  int idx = blockIdx.x*256 + threadIdx.x;
  if (idx >= NN*32) return;
  int row = idx >> 5;
  int c4 = (idx & 31) * 4;
  float4 v  = *(const float4*)&h[(size_t)row*F + c4];
  float4 sm = *(const float4*)&stats[c4];
  float4 sq = *(const float4*)&stats[128 + c4];
  float4 g  = *(const float4*)&gamma[c4];
  float4 bt = *(const float4*)&beta[c4];
  const float invN = 1.f / (float)NN;
  float r0;
  float4 y;
  { float m = sm.x*invN; float var = sq.x*invN - m*m; r0 = rsqrtf(var + BNEPS);
    float z = (v.x - m)*r0*g.x + bt.x; y.x = (z > 0.f) ? z : 0.1f*z; }
  { float m = sm.y*invN; float var = sq.y*invN - m*m; r0 = rsqrtf(var + BNEPS);
    float z = (v.y - m)*r0*g.y + bt.y; y.y = (z > 0.f) ? z : 0.1f*z; }
  { float m = sm.z*invN; float var = sq.z*invN - m*m; r0 = rsqrtf(var + BNEPS);
    float z = (v.z - m)*r0*g.z + bt.z; y.z = (z > 0.f) ? z : 0.1f*z; }
  { float m = sm.w*invN; float var = sq.w*invN - m*m; r0 = rsqrtf(var + BNEPS);
    float z = (v.w - m)*r0*g.w + bt.w; y.w = (z > 0.f) ? z : 0.1f*z; }
  *(float4*)&outp[(size_t)row*F + c4] = y;
}

__global__ __launch_bounds__(256) void k_l2norm(float* __restrict__ outp) {
  __shared__ float s[256];
  int t = threadIdx.x;
  int g = t >> 7;
  int c = t & 127;
  int row = blockIdx.x*2 + g;
  float v = outp[(size_t)row*F + c];
  s[t] = v*v;
  __syncthreads();
  for (int o = 64; o > 0; o >>= 1) {
    if ((t & 127) < o) s[t] += s[t+o];
    __syncthreads();
  }
  float nrm = fmaxf(sqrtf(s[t & ~127]), 1e-12f);
  outp[(size_t)row*F + c] = v / nrm;
}

// ----------------------------- host launcher -----------------------------
extern "C" void kernel_launch(void* const* d_in, const int* in_sizes, int n_in,
                              void* d_out, int out_size, void* d_ws, size_t ws_size,
                              hipStream_t stream) {
  const float* x      = (const float*)d_in[0];
  const int*   ei     = (const int*)d_in[1];
  const int*   etp    = (const int*)d_in[2];
  const float* basis[3] = {(const float*)d_in[3], (const float*)d_in[7],  (const float*)d_in[11]};
  const float* comp[3]  = {(const float*)d_in[4], (const float*)d_in[8],  (const float*)d_in[12]};
  const float* root[3]  = {(const float*)d_in[5], (const float*)d_in[9],  (const float*)d_in[13]};
  const float* bias[3]  = {(const float*)d_in[6], (const float*)d_in[10], (const float*)d_in[14]};
  const float* gamma[2] = {(const float*)d_in[15], (const float*)d_in[17]};
  const float* beta[2]  = {(const float*)d_in[16], (const float*)d_in[18]};
  const int* srcv = ei;
  const int* dstv = ei + EE;
  float* out = (float*)d_out;

  char* w = (char*)d_ws;
  size_t p = 0;
  auto take = [&](size_t bytes) -> void* {
    void* q = w + p;
    p = (p + bytes + 255) & ~(size_t)255;
    return q;
  };
  unsigned* cnt   = (unsigned*)take((size_t)NSEG*4);
  unsigned* off   = (unsigned*)take((size_t)NSEG*4);
  unsigned* fillc = (unsigned*)take((size_t)NSEG*4);
  int*      csr   = (int*)     take((size_t)EE*4);
  unsigned* bsum  = (unsigned*)take(1024*4);
  unsigned short* WB = (unsigned short*)take((size_t)KDIM*F*2);
  float*    stats = (float*)   take(256*4);
  float*    wsA   = (float*)   take((size_t)NN*F*4);
  float*    wsB   = (float*)   take((size_t)NN*F*4);
  (void)ws_size;

  // -------- static graph preprocessing --------
  hipMemsetAsync(cnt,   0, (size_t)NSEG*4, stream);
  hipMemsetAsync(fillc, 0, (size_t)NSEG*4, stream);
  k_count<<<(EE+255)/256, 256, 0, stream>>>(dstv, etp, cnt);
  int nb1 = (NSEG + 2047)/2048;
  k_scan1<<<nb1, 256, 0, stream>>>(cnt, off, bsum);
  k_scan2<<<1, 512, 0, stream>>>(bsum, nb1);
  k_scan3<<<(NSEG+255)/256, 256, 0, stream>>>(off, bsum);
  k_fill<<<(EE+255)/256, 256, 0, stream>>>(srcv, dstv, etp, off, fillc, csr);

  // -------- 3 layers --------
  int NB = (NN + NT - 1) / NT;
  for (int l = 0; l < 3; l++) {
    const float* hin = (l == 0) ? x : wsB;
    float* hraw = (l == 2) ? out : wsA;
    dim3 gw(NKT, 8);
    k_makeW<<<gw, 64, 0, stream>>>(basis[l], comp[l], root[l], WB);
    k_fused<<<NB, 256, 0, stream>>>(hin, off, cnt, csr, WB, bias[l], hraw, NN);
    if (l < 2) {
      hipMemsetAsync(stats, 0, 256*4, stream);
      k_bnstats<<<(NN+511)/512, 256, 0, stream>>>(hraw, stats);
      k_bnapply<<<(NN*32+255)/256, 256, 0, stream>>>(hraw, stats, gamma[l], beta[l], wsB);
    }
  }
  k_l2norm<<<NN/2, 256, 0, stream>>>(out);
}

// Round 4
// 897.950 us; speedup vs baseline: 3.2776x; 1.2939x over previous
//
#include <hip/hip_runtime.h>

#define NN 100000
#define EE 1600000
#define RRR 8
#define NSEG (NN*RRR)
#define F 128
#define KDIM 1152          // 8 relations * 128 + self(root) 128
#define NKT 36             // KDIM/32
#define BNEPS 1e-5f

typedef __attribute__((ext_vector_type(8))) short bf16x8;
typedef __attribute__((ext_vector_type(8))) unsigned short u16x8;
typedef __attribute__((ext_vector_type(4))) float f32x4;

static __device__ __forceinline__ unsigned short bf16r(float f) {
  unsigned u = __float_as_uint(f);
  u += 0x7fffu + ((u >> 16) & 1u);
  return (unsigned short)(u >> 16);
}
static __device__ __forceinline__ float b2f(unsigned short s) {
  return __uint_as_float((unsigned)s << 16);
}

// ----------------------------- setup kernels -----------------------------
__global__ void k_count(const int* __restrict__ dst, const int* __restrict__ et,
                        unsigned* __restrict__ cnt) {
  int e = blockIdx.x*256 + threadIdx.x;
  if (e < EE) {
    int seg = dst[e]*RRR + et[e];
    atomicAdd(&cnt[seg], 1u);
  }
}

__global__ void k_scan1(const unsigned* __restrict__ cnt, unsigned* __restrict__ off,
                        unsigned* __restrict__ bsum) {
  __shared__ unsigned s[256];
  int t = threadIdx.x;
  int base = blockIdx.x*2048 + t*8;
  unsigned loc[8];
  unsigned tot = 0;
#pragma unroll
  for (int j = 0; j < 8; j++) {
    unsigned v = (base+j < NSEG) ? cnt[base+j] : 0u;
    loc[j] = tot;
    tot += v;
  }
  s[t] = tot;
  __syncthreads();
  for (int d = 1; d < 256; d <<= 1) {
    unsigned v = (t >= d) ? s[t-d] : 0u;
    __syncthreads();
    s[t] += v;
    __syncthreads();
  }
  unsigned tbase = s[t] - tot;
#pragma unroll
  for (int j = 0; j < 8; j++)
    if (base+j < NSEG) off[base+j] = tbase + loc[j];
  if (t == 255) bsum[blockIdx.x] = s[255];
}

__global__ void k_scan2(unsigned* bsum, int nb) {
  __shared__ unsigned s[512];
  int t = threadIdx.x;
  unsigned v = (t < nb) ? bsum[t] : 0u;
  s[t] = v;
  __syncthreads();
  for (int d = 1; d < 512; d <<= 1) {
    unsigned u = (t >= d) ? s[t-d] : 0u;
    __syncthreads();
    s[t] += u;
    __syncthreads();
  }
  if (t < nb) bsum[t] = (t == 0) ? 0u : s[t-1];
}

__global__ void k_scan3(unsigned* off, const unsigned* __restrict__ bsum) {
  int i = blockIdx.x*256 + threadIdx.x;
  if (i < NSEG) off[i] += bsum[i >> 11];
}

__global__ void k_fill(const int* __restrict__ src, const int* __restrict__ dst,
                       const int* __restrict__ et, const unsigned* __restrict__ off,
                       unsigned* __restrict__ fillc, int* __restrict__ csr) {
  int e = blockIdx.x*256 + threadIdx.x;
  if (e < EE) {
    int seg = dst[e]*RRR + et[e];
    unsigned pos = off[seg] + atomicAdd(&fillc[seg], 1u);
    csr[pos] = src[e];
  }
}

// x (f32) -> xb (bf16)
__global__ void k_cvt(const float* __restrict__ x, unsigned short* __restrict__ xb) {
  int i = blockIdx.x*256 + threadIdx.x;
  if (i < NN*32) {
    float4 v = ((const float4*)x)[i];
    ushort4 o;
    o.x = bf16r(v.x); o.y = bf16r(v.y); o.z = bf16r(v.z); o.w = bf16r(v.w);
    ((ushort4*)xb)[i] = o;
  }
}

// WB in B-fragment layout (bf16): WB[((kt*8 + ct)*64 + lane)*8 + j]
//   = Wcat[k][o],  k = kt*32 + (lane>>4)*8 + j,  o = ct*16 + (lane&15)
__global__ void k_makeW(const float* __restrict__ basis, const float* __restrict__ comp,
                        const float* __restrict__ root, unsigned short* __restrict__ WB) {
  int kt = blockIdx.x;        // 0..35
  int ct = blockIdx.y;        // 0..7
  int lane = threadIdx.x;     // 0..63
  int o = ct*16 + (lane & 15);
  int kbase = kt*32 + (lane >> 4)*8;
  unsigned short v[8];
#pragma unroll
  for (int j = 0; j < 8; j++) {
    int k = kbase + j;
    float val;
    if (k < 1024) {
      int r = k >> 7, i = k & 127;
      val = 0.f;
#pragma unroll
      for (int b = 0; b < 8; b++)
        val += comp[r*8+b] * basis[(b*F + i)*F + o];
    } else {
      val = root[(k - 1024)*F + o];
    }
    v[j] = bf16r(val);
  }
  unsigned short* dst = WB + ((size_t)(kt*8 + ct)*64 + lane)*8;
#pragma unroll
  for (int j = 0; j < 8; j++) dst[j] = v[j];
}

// ----------------------------- aggregation -----------------------------
// bf16 table. Block = 2 nodes (16 segments), 16 lanes/segment (ushort8 each).
// Wave = 4 independent segments -> 4-8 gathers in flight.
__global__ __launch_bounds__(256) void k_agg(const unsigned short* __restrict__ hb,
    const unsigned* __restrict__ off, const unsigned* __restrict__ cnt,
    const int* __restrict__ csr, unsigned short* __restrict__ Mean,
    int base, int count) {
  int t = threadIdx.x;
  int sl = t & 15;
  int c8 = sl * 8;
  int sidx = t >> 4;          // 0..15
  int nl = sidx >> 3;         // 0..1
  int r  = sidx & 7;
  int nloc = blockIdx.x*2 + nl;
  if (nloc > count-1) nloc = count-1;
  int node = base + nloc;
  int seg = node*RRR + r;
  unsigned b0 = off[seg];
  unsigned k = cnt[seg];
  float a[8];
#pragma unroll
  for (int u = 0; u < 8; u++) a[u] = 0.f;
  unsigned j = 0;
  for (; j + 2 <= k; j += 2) {
    int iA = csr[b0+j];
    int iB = csr[b0+j+1];
    u16x8 va = *(const u16x8*)&hb[(size_t)iA*F + c8];
    u16x8 vb = *(const u16x8*)&hb[(size_t)iB*F + c8];
#pragma unroll
    for (int u = 0; u < 8; u++) a[u] += b2f(va[u]) + b2f(vb[u]);
  }
  if (j < k) {
    int iA = csr[b0+j];
    u16x8 va = *(const u16x8*)&hb[(size_t)iA*F + c8];
#pragma unroll
    for (int u = 0; u < 8; u++) a[u] += b2f(va[u]);
  }
  float inv = k ? 1.f/(float)k : 0.f;
  u16x8 o;
#pragma unroll
  for (int u = 0; u < 8; u++) o[u] = bf16r(a[u]*inv);
  size_t mrow = (size_t)nloc * KDIM;
  *(u16x8*)&Mean[mrow + r*F + c8] = o;
  if (r == 0)
    *(u16x8*)&Mean[mrow + 1024 + c8] = *(const u16x8*)&hb[(size_t)node*F + c8];
}

// ----------------------------- GEMM (+BN stats / +L2 norm) -----------------------------
// C[count x 128] = Mean[count x 1152](bf16) @ WB + bias. 4 waves, wave w =
// rows w*32..+32, all 128 cols. mode 0: accumulate BN stats. mode 1: fused
// row L2-normalize (final layer).
__global__ __launch_bounds__(256) void k_gemm(const unsigned short* __restrict__ Mean,
    const unsigned short* __restrict__ WB, const float* __restrict__ bias,
    float* __restrict__ outp, float* __restrict__ stats,
    int outBase, int count, int mode) {
  __shared__ float s_sum[128];
  __shared__ float s_sq[128];
  int t = threadIdx.x;
  int wave = t >> 6;
  int lane = t & 63;
  int rbase = blockIdx.x*128 + wave*32;
  int rlo = lane & 15;
  int kg = lane >> 4;
  int r0 = rbase + rlo;       if (r0 > count-1) r0 = count-1;
  int r1 = rbase + 16 + rlo;  if (r1 > count-1) r1 = count-1;
  const unsigned short* a0p = Mean + (size_t)r0*KDIM + kg*8;
  const unsigned short* a1p = Mean + (size_t)r1*KDIM + kg*8;
  const unsigned short* bp  = WB + (size_t)lane*8;

  if (mode == 0 && t < 128) { s_sum[t] = 0.f; s_sq[t] = 0.f; }

  f32x4 acc[2][8];
#pragma unroll
  for (int i = 0; i < 2; i++)
#pragma unroll
    for (int j = 0; j < 8; j++) acc[i][j] = (f32x4){0.f,0.f,0.f,0.f};

  for (int kt = 0; kt < NKT; kt++) {
    bf16x8 a0 = *(const bf16x8*)(a0p + kt*32);
    bf16x8 a1 = *(const bf16x8*)(a1p + kt*32);
#pragma unroll
    for (int ct = 0; ct < 8; ct++) {
      bf16x8 b = *(const bf16x8*)(bp + (size_t)(kt*8 + ct)*64*8);
      acc[0][ct] = __builtin_amdgcn_mfma_f32_16x16x32_bf16(a0, b, acc[0][ct], 0, 0, 0);
      acc[1][ct] = __builtin_amdgcn_mfma_f32_16x16x32_bf16(a1, b, acc[1][ct], 0, 0, 0);
    }
  }

  float bv[8];
#pragma unroll
  for (int ct = 0; ct < 8; ct++) bv[ct] = bias[ct*16 + rlo];

  if (mode == 0) {
    __syncthreads();  // s_sum/s_sq zeroed
    float psum[8], psq[8];
#pragma unroll
    for (int ct = 0; ct < 8; ct++) { psum[ct] = 0.f; psq[ct] = 0.f; }
    // C/D layout: col = ct*16 + (lane&15), row = rt*16 + kg*4 + i
#pragma unroll
    for (int rt = 0; rt < 2; rt++) {
#pragma unroll
      for (int i = 0; i < 4; i++) {
        int row = rbase + rt*16 + kg*4 + i;
        if (row < count) {
          float* orow = outp + (size_t)(outBase + row)*F;
#pragma unroll
          for (int ct = 0; ct < 8; ct++) {
            float y = acc[rt][ct][i] + bv[ct];
            orow[ct*16 + rlo] = y;
            psum[ct] += y;
            psq[ct]  += y*y;
          }
        }
      }
    }
#pragma unroll
    for (int ct = 0; ct < 8; ct++) {
      atomicAdd(&s_sum[ct*16 + rlo], psum[ct]);
      atomicAdd(&s_sq [ct*16 + rlo], psq[ct]);
    }
    __syncthreads();
    if (t < 128) {
      atomicAdd(&stats[t],       s_sum[t]);
      atomicAdd(&stats[128 + t], s_sq[t]);
    }
  } else {
    // final layer: fused row L2-normalize; row's 128 cols live in this
    // 16-lane group (rlo 0..15) x 8 ct values.
#pragma unroll
    for (int rt = 0; rt < 2; rt++) {
#pragma unroll
      for (int i = 0; i < 4; i++) {
        int row = rbase + rt*16 + kg*4 + i;
        float y[8];
        float ss = 0.f;
#pragma unroll
        for (int ct = 0; ct < 8; ct++) {
          y[ct] = acc[rt][ct][i] + bv[ct];
          ss += y[ct]*y[ct];
        }
#pragma unroll
        for (int m = 1; m < 16; m <<= 1)
          ss += __shfl_xor(ss, m, 64);
        float inv = 1.f / fmaxf(sqrtf(ss), 1e-12f);
        if (row < count) {
          float* orow = outp + (size_t)(outBase + row)*F;
#pragma unroll
          for (int ct = 0; ct < 8; ct++)
            orow[ct*16 + rlo] = y[ct]*inv;
        }
      }
    }
  }
}

// BN apply + LeakyReLU, writes bf16 table for next layer's gathers
__global__ __launch_bounds__(256) void k_bnapply(const float* __restrict__ h,
    const float* __restrict__ stats, const float* __restrict__ gamma,
    const float* __restrict__ beta, unsigned short* __restrict__ outp) {
  int idx = blockIdx.x*256 + threadIdx.x;
  if (idx >= NN*32) return;
  int row = idx >> 5;
  int c4 = (idx & 31) * 4;
  float4 v  = *(const float4*)&h[(size_t)row*F + c4];
  float4 sm = *(const float4*)&stats[c4];
  float4 sq = *(const float4*)&stats[128 + c4];
  float4 g  = *(const float4*)&gamma[c4];
  float4 bt = *(const float4*)&beta[c4];
  const float invN = 1.f / (float)NN;
  ushort4 o;
  { float m = sm.x*invN; float var = sq.x*invN - m*m; float r0 = rsqrtf(var + BNEPS);
    float z = (v.x - m)*r0*g.x + bt.x; o.x = bf16r((z > 0.f) ? z : 0.1f*z); }
  { float m = sm.y*invN; float var = sq.y*invN - m*m; float r0 = rsqrtf(var + BNEPS);
    float z = (v.y - m)*r0*g.y + bt.y; o.y = bf16r((z > 0.f) ? z : 0.1f*z); }
  { float m = sm.z*invN; float var = sq.z*invN - m*m; float r0 = rsqrtf(var + BNEPS);
    float z = (v.z - m)*r0*g.z + bt.z; o.z = bf16r((z > 0.f) ? z : 0.1f*z); }
  { float m = sm.w*invN; float var = sq.w*invN - m*m; float r0 = rsqrtf(var + BNEPS);
    float z = (v.w - m)*r0*g.w + bt.w; o.w = bf16r((z > 0.f) ? z : 0.1f*z); }
  *(ushort4*)&outp[(size_t)row*F + c4] = o;
}

// ----------------------------- host launcher -----------------------------
extern "C" void kernel_launch(void* const* d_in, const int* in_sizes, int n_in,
                              void* d_out, int out_size, void* d_ws, size_t ws_size,
                              hipStream_t stream) {
  const float* x      = (const float*)d_in[0];
  const int*   ei     = (const int*)d_in[1];
  const int*   etp    = (const int*)d_in[2];
  const float* basis[3] = {(const float*)d_in[3], (const float*)d_in[7],  (const float*)d_in[11]};
  const float* comp[3]  = {(const float*)d_in[4], (const float*)d_in[8],  (const float*)d_in[12]};
  const float* root[3]  = {(const float*)d_in[5], (const float*)d_in[9],  (const float*)d_in[13]};
  const float* bias[3]  = {(const float*)d_in[6], (const float*)d_in[10], (const float*)d_in[14]};
  const float* gamma[2] = {(const float*)d_in[15], (const float*)d_in[17]};
  const float* beta[2]  = {(const float*)d_in[16], (const float*)d_in[18]};
  const int* srcv = ei;
  const int* dstv = ei + EE;
  float* out = (float*)d_out;

  char* w = (char*)d_ws;
  size_t p = 0;
  auto take = [&](size_t bytes) -> void* {
    void* q = w + p;
    p = (p + bytes + 255) & ~(size_t)255;
    return q;
  };
  unsigned* cnt   = (unsigned*)take((size_t)NSEG*4);
  unsigned* off   = (unsigned*)take((size_t)NSEG*4);
  unsigned* fillc = (unsigned*)take((size_t)NSEG*4);
  int*      csr   = (int*)     take((size_t)EE*4);
  unsigned* bsum  = (unsigned*)take(1024*4);
  unsigned short* WB = (unsigned short*)take((size_t)KDIM*F*2);
  float*    stats = (float*)   take(256*4);
  float*    wsA   = (float*)   take((size_t)NN*F*4);       // f32 conv output
  unsigned short* wsBb = (unsigned short*)take((size_t)NN*F*2);  // bf16 BN output
  unsigned short* xb   = (unsigned short*)take((size_t)NN*F*2);  // bf16 x
  size_t avail = (ws_size > p) ? (ws_size - p) : 0;
  long long chmax = (long long)(avail / ((size_t)KDIM*2));
  int CH = (chmax > NN) ? NN : (int)chmax;
  if (CH < 2) CH = 2;
  unsigned short* Mean = (unsigned short*)(w + p);

  // -------- static graph preprocessing --------
  hipMemsetAsync(cnt,   0, (size_t)NSEG*4, stream);
  hipMemsetAsync(fillc, 0, (size_t)NSEG*4, stream);
  k_count<<<(EE+255)/256, 256, 0, stream>>>(dstv, etp, cnt);
  int nb1 = (NSEG + 2047)/2048;
  k_scan1<<<nb1, 256, 0, stream>>>(cnt, off, bsum);
  k_scan2<<<1, 512, 0, stream>>>(bsum, nb1);
  k_scan3<<<(NSEG+255)/256, 256, 0, stream>>>(off, bsum);
  k_fill<<<(EE+255)/256, 256, 0, stream>>>(srcv, dstv, etp, off, fillc, csr);
  k_cvt<<<(NN*32+255)/256, 256, 0, stream>>>(x, xb);

  // -------- 3 layers --------
  for (int l = 0; l < 3; l++) {
    const unsigned short* hin = (l == 0) ? xb : wsBb;
    float* hraw = (l == 2) ? out : wsA;
    int mode = (l == 2) ? 1 : 0;
    dim3 gw(NKT, 8);
    k_makeW<<<gw, 64, 0, stream>>>(basis[l], comp[l], root[l], WB);
    if (l < 2) hipMemsetAsync(stats, 0, 256*4, stream);
    for (int b0n = 0; b0n < NN; b0n += CH) {
      int cc = NN - b0n; if (cc > CH) cc = CH;
      k_agg<<<(cc+1)/2, 256, 0, stream>>>(hin, off, cnt, csr, Mean, b0n, cc);
      k_gemm<<<(cc+127)/128, 256, 0, stream>>>(Mean, WB, bias[l], hraw, stats, b0n, cc, mode);
    }
    if (l < 2)
      k_bnapply<<<(NN*32+255)/256, 256, 0, stream>>>(hraw, stats, gamma[l], beta[l], wsBb);
  }
}